// Round 1
// baseline (2189.218 us; speedup 1.0000x reference)
//
#include <hip/hip_runtime.h>
#include <math.h>

#define N_DENSE  13
#define N_SPARSE 26
#define VOCAB    100000
#define EMB      64
#define NH       12
#define NPAIR    325
#define ESTR     68       // padded row stride (floats), 16B aligned, bank-spread
#define TEMP_INV 10.0f

__global__ __launch_bounds__(256) void afm_kernel(
    const float* __restrict__ dense_x,
    const int*   __restrict__ sparse_idx,
    const float* __restrict__ emb,
    const float* __restrict__ attn_W,
    const float* __restrict__ attn_b,
    const float* __restrict__ proj_W,
    const float* __restrict__ proj_b,
    const float* __restrict__ lin_W,
    const float* __restrict__ lin_b,
    const float* __restrict__ pred_W,
    const float* __restrict__ pred_b,
    float* __restrict__ out)
{
    const int row  = blockIdx.x;
    const int tid  = threadIdx.x;
    const int lane = tid & 63;
    const int wv   = tid >> 6;

    __shared__ __align__(16) float e_s[N_SPARSE][ESTR];
    __shared__ __align__(16) float w_s[EMB * NH];
    __shared__ float b_s[NH];
    __shared__ float pw_s[NH];
    __shared__ float predw_s[EMB];
    __shared__ float expv_s[NPAIR];
    __shared__ float red_s[8];
    __shared__ float att_s[4][EMB];
    __shared__ float part1_s;
    __shared__ float pb_s;    // proj_b
    __shared__ float pb2_s;   // pred_b
    __shared__ int   sidx_s[N_SPARSE];

    // ---- stage small params + sparse indices ----
    if (tid < N_SPARSE) sidx_s[tid] = sparse_idx[row * N_SPARSE + tid];
    if (tid < NH)  { b_s[tid] = attn_b[tid]; pw_s[tid] = proj_W[tid]; }
    if (tid < EMB) predw_s[tid] = pred_W[tid];
    if (tid == 0)  { pb_s = proj_b[0]; pb2_s = pred_b[0]; }
    for (int idx = tid; idx < EMB * NH; idx += 256) w_s[idx] = attn_W[idx];
    __syncthreads();

    // ---- gather embeddings into LDS ----
    for (int idx = tid; idx < N_SPARSE * EMB; idx += 256) {
        int f = idx >> 6, d = idx & 63;
        e_s[f][d] = emb[((size_t)f * VOCAB + (size_t)sidx_s[f]) * EMB + d];
    }
    // ---- linear part (part_1), exact f32 ----
    if (tid == 0) {
        float p1 = lin_b[0];
        for (int c = 0; c < N_DENSE; ++c)
            p1 += dense_x[row * N_DENSE + c] * lin_W[c];
        for (int f = 0; f < N_SPARSE; ++f)
            p1 += (float)sidx_s[f] * lin_W[N_DENSE + f];
        part1_s = p1;
    }
    __syncthreads();

    // ---- per-pair attention logits (thread-per-pair, 2 ragged rounds) ----
    const float4* wq = reinterpret_cast<const float4*>(w_s);
    float my_logit[2];
    int   my_p[2];
    float lmax = -INFINITY;

    for (int r2 = 0; r2 < 2; ++r2) {
        int p = tid + r2 * 256;
        my_p[r2] = p;
        my_logit[r2] = -INFINITY;
        if (p < NPAIR) {
            // decode pair p -> (i, j), triu order
            int i = 0, rem = p;
            while (rem >= (N_SPARSE - 1 - i)) { rem -= (N_SPARSE - 1 - i); ++i; }
            int j = i + 1 + rem;

            float h[NH];
            #pragma unroll
            for (int k = 0; k < NH; ++k) h[k] = b_s[k];

            const float4* ei = reinterpret_cast<const float4*>(&e_s[i][0]);
            const float4* ej = reinterpret_cast<const float4*>(&e_s[j][0]);

            #pragma unroll
            for (int d4 = 0; d4 < 16; ++d4) {
                float4 a = ei[d4];
                float4 b = ej[d4];
                float c[4] = { a.x * b.x, a.y * b.y, a.z * b.z, a.w * b.w };
                #pragma unroll
                for (int t = 0; t < 12; ++t) {
                    float4 w4 = wq[d4 * 12 + t];
                    const int f0 = 4 * t;
                    h[(f0 + 0) % 12] = fmaf(c[(f0 + 0) / 12], w4.x, h[(f0 + 0) % 12]);
                    h[(f0 + 1) % 12] = fmaf(c[(f0 + 1) / 12], w4.y, h[(f0 + 1) % 12]);
                    h[(f0 + 2) % 12] = fmaf(c[(f0 + 2) / 12], w4.z, h[(f0 + 2) % 12]);
                    h[(f0 + 3) % 12] = fmaf(c[(f0 + 3) / 12], w4.w, h[(f0 + 3) % 12]);
                }
            }
            float lg = pb_s;
            #pragma unroll
            for (int k = 0; k < NH; ++k)
                lg = fmaf(fmaxf(h[k], 0.0f), pw_s[k], lg);
            lg *= TEMP_INV;
            my_logit[r2] = lg;
            lmax = fmaxf(lmax, lg);
        }
    }

    // ---- block max reduce (softmax stability) ----
    #pragma unroll
    for (int o = 32; o > 0; o >>= 1) lmax = fmaxf(lmax, __shfl_xor(lmax, o));
    if (lane == 0) red_s[wv] = lmax;
    __syncthreads();
    float gmax = fmaxf(fmaxf(red_s[0], red_s[1]), fmaxf(red_s[2], red_s[3]));

    // ---- exp + sum reduce ----
    float lsum = 0.0f;
    for (int r2 = 0; r2 < 2; ++r2) {
        int p = my_p[r2];
        if (p < NPAIR) {
            float ev = __expf(my_logit[r2] - gmax);
            expv_s[p] = ev;
            lsum += ev;
        }
    }
    #pragma unroll
    for (int o = 32; o > 0; o >>= 1) lsum += __shfl_xor(lsum, o);
    if (lane == 0) red_s[4 + wv] = lsum;
    __syncthreads();
    float gsum = red_s[4] + red_s[5] + red_s[6] + red_s[7];

    // ---- weighted sum over pairs: wave wv handles pair range, lane = dim ----
    {
        int lo = (NPAIR * wv) >> 2;
        int hi = (NPAIR * (wv + 1)) >> 2;
        int i = 0, rem = lo;
        while (rem >= (N_SPARSE - 1 - i)) { rem -= (N_SPARSE - 1 - i); ++i; }
        int j = i + 1 + rem;
        float acc = 0.0f;
        for (int p = lo; p < hi; ++p) {
            float s = expv_s[p];
            acc = fmaf(s, e_s[i][lane] * e_s[j][lane], acc);
            if (++j == N_SPARSE) { ++i; j = i + 1; }
        }
        att_s[wv][lane] = acc;
    }
    __syncthreads();

    // ---- combine waves, project with pred_W, final sigmoid ----
    if (wv == 0) {
        float a = att_s[0][lane] + att_s[1][lane] + att_s[2][lane] + att_s[3][lane];
        float v = a * predw_s[lane];
        #pragma unroll
        for (int o = 32; o > 0; o >>= 1) v += __shfl_xor(v, o);
        if (lane == 0) {
            float part2 = v / gsum + pb2_s;
            float z = part1_s + part2;
            out[row] = 1.0f / (1.0f + __expf(-z));
        }
    }
}

extern "C" void kernel_launch(void* const* d_in, const int* in_sizes, int n_in,
                              void* d_out, int out_size, void* d_ws, size_t ws_size,
                              hipStream_t stream)
{
    const float* dense_x = (const float*)d_in[0];
    const int*   sparse  = (const int*)  d_in[1];
    const float* emb     = (const float*)d_in[2];
    const float* attn_W  = (const float*)d_in[3];
    const float* attn_b  = (const float*)d_in[4];
    const float* proj_W  = (const float*)d_in[5];
    const float* proj_b  = (const float*)d_in[6];
    const float* lin_W   = (const float*)d_in[7];
    const float* lin_b   = (const float*)d_in[8];
    const float* pred_W  = (const float*)d_in[9];
    const float* pred_b  = (const float*)d_in[10];
    float* out = (float*)d_out;

    int rows = in_sizes[0] / N_DENSE;   // 8192
    afm_kernel<<<rows, 256, 0, stream>>>(dense_x, sparse, emb, attn_W, attn_b,
                                         proj_W, proj_b, lin_W, lin_b,
                                         pred_W, pred_b, out);
}

// Round 2
// 150.188 us; speedup vs baseline: 14.5765x; 14.5765x over previous
//
#include <hip/hip_runtime.h>
#include <math.h>

#define N_DENSE  13
#define N_SPARSE 26
#define VOCAB    100000
#define EMB      64
#define NH       12
#define NPAIR    325
#define ESTR     68       // padded row stride (floats): 16B-aligned, bank-period 8
#define NWAVE    6
#define BLOCK    384
#define TEMP_INV 10.0f

__global__ __launch_bounds__(BLOCK) void afm_kernel(
    const float* __restrict__ dense_x,
    const int*   __restrict__ sparse_idx,
    const float* __restrict__ emb,
    const float* __restrict__ attn_W,
    const float* __restrict__ attn_b,
    const float* __restrict__ proj_W,
    const float* __restrict__ proj_b,
    const float* __restrict__ lin_W,
    const float* __restrict__ lin_b,
    const float* __restrict__ pred_W,
    const float* __restrict__ pred_b,
    float* __restrict__ out)
{
    const int row  = blockIdx.x;
    const int tid  = threadIdx.x;
    const int lane = tid & 63;
    const int wv   = tid >> 6;

    __shared__ __align__(16) float e_s[N_SPARSE][ESTR];
    __shared__ float expv_s[NPAIR];
    __shared__ float redmax_s[NWAVE];
    __shared__ float redsum_s[NWAVE];
    __shared__ float att_s[NWAVE][EMB];
    __shared__ float part1_s;
    __shared__ int   sidx_s[N_SPARSE];

    if (tid < N_SPARSE) sidx_s[tid] = sparse_idx[row * N_SPARSE + tid];
    __syncthreads();

    // ---- gather embeddings into LDS (float4, coalesced 256B rows) ----
    for (int q = tid; q < N_SPARSE * 16; q += BLOCK) {
        int f = q >> 4, d4 = q & 15;
        const float4* src = reinterpret_cast<const float4*>(
            emb + ((size_t)f * VOCAB + (size_t)sidx_s[f]) * EMB);
        reinterpret_cast<float4*>(&e_s[f][0])[d4] = src[d4];
    }

    // ---- part_1 (exact f32), wave 0, lane-parallel over 39 terms ----
    if (wv == 0) {
        float t = 0.0f;
        if (lane < N_DENSE)
            t = dense_x[row * N_DENSE + lane] * lin_W[lane];
        else if (lane < N_DENSE + N_SPARSE)
            t = (float)sidx_s[lane - N_DENSE] * lin_W[lane];
        #pragma unroll
        for (int o = 32; o > 0; o >>= 1) t += __shfl_xor(t, o);
        if (lane == 0) part1_s = t + lin_b[0];
    }
    __syncthreads();

    // ---- attention logits: one pair per thread, UNIFORM control flow ----
    // (uniform CF => attn_W/attn_b/proj_W reads become s_load into SGPRs)
    const bool valid = (tid < NPAIR);
    int pc = valid ? tid : 0;
    int i = 0, rem = pc;
    while (rem >= (N_SPARSE - 1 - i)) { rem -= (N_SPARSE - 1 - i); ++i; }
    const int j = i + 1 + rem;

    float h[NH];
    #pragma unroll
    for (int k = 0; k < NH; ++k) h[k] = attn_b[k];

    const float4* ei = reinterpret_cast<const float4*>(&e_s[i][0]);
    const float4* ej = reinterpret_cast<const float4*>(&e_s[j][0]);
    const float4* wg = reinterpret_cast<const float4*>(attn_W);  // W[d][k], f4 idx d*3+k/4

    #pragma unroll 2
    for (int d4 = 0; d4 < 16; ++d4) {
        float4 a = ei[d4];
        float4 b = ej[d4];
        float c0 = a.x * b.x, c1 = a.y * b.y, c2 = a.z * b.z, c3 = a.w * b.w;
        const int base = d4 * 12;   // 4 dims * 3 float4 each
        float4 w;
#define WROW(cx, o) \
        w = wg[base + (o)*3 + 0]; \
        h[0] = fmaf(cx, w.x, h[0]);  h[1] = fmaf(cx, w.y, h[1]); \
        h[2] = fmaf(cx, w.z, h[2]);  h[3] = fmaf(cx, w.w, h[3]); \
        w = wg[base + (o)*3 + 1]; \
        h[4] = fmaf(cx, w.x, h[4]);  h[5] = fmaf(cx, w.y, h[5]); \
        h[6] = fmaf(cx, w.z, h[6]);  h[7] = fmaf(cx, w.w, h[7]); \
        w = wg[base + (o)*3 + 2]; \
        h[8] = fmaf(cx, w.x, h[8]);  h[9] = fmaf(cx, w.y, h[9]); \
        h[10] = fmaf(cx, w.z, h[10]); h[11] = fmaf(cx, w.w, h[11]);
        WROW(c0, 0) WROW(c1, 1) WROW(c2, 2) WROW(c3, 3)
#undef WROW
    }

    float lg = proj_b[0];
    #pragma unroll
    for (int k = 0; k < NH; ++k)
        lg = fmaf(fmaxf(h[k], 0.0f), proj_W[k], lg);
    lg *= TEMP_INV;
    if (!valid) lg = -INFINITY;

    // ---- block softmax: max ----
    float lmax = lg;
    #pragma unroll
    for (int o = 32; o > 0; o >>= 1) lmax = fmaxf(lmax, __shfl_xor(lmax, o));
    if (lane == 0) redmax_s[wv] = lmax;
    __syncthreads();
    float gmax = redmax_s[0];
    #pragma unroll
    for (int w2 = 1; w2 < NWAVE; ++w2) gmax = fmaxf(gmax, redmax_s[w2]);

    // ---- exp + sum ----
    float ev = valid ? __expf(lg - gmax) : 0.0f;
    if (valid) expv_s[tid] = ev;
    float lsum = ev;
    #pragma unroll
    for (int o = 32; o > 0; o >>= 1) lsum += __shfl_xor(lsum, o);
    if (lane == 0) redsum_s[wv] = lsum;
    __syncthreads();
    float gsum = redsum_s[0];
    #pragma unroll
    for (int w2 = 1; w2 < NWAVE; ++w2) gsum += redsum_s[w2];

    // ---- weighted sum over pairs: wave = pair chunk, lane = dim ----
    {
        int lo = (NPAIR * wv) / NWAVE;
        int hi = (NPAIR * (wv + 1)) / NWAVE;
        int ii = 0, rem2 = lo;
        while (rem2 >= (N_SPARSE - 1 - ii)) { rem2 -= (N_SPARSE - 1 - ii); ++ii; }
        int jj = ii + 1 + rem2;
        float acc = 0.0f;
        for (int p = lo; p < hi; ++p) {
            acc = fmaf(expv_s[p], e_s[ii][lane] * e_s[jj][lane], acc);
            if (++jj == N_SPARSE) { ++ii; jj = ii + 1; }
        }
        att_s[wv][lane] = acc;
    }
    __syncthreads();

    // ---- combine, project, sigmoid ----
    if (wv == 0) {
        float a = 0.0f;
        #pragma unroll
        for (int w2 = 0; w2 < NWAVE; ++w2) a += att_s[w2][lane];
        float v = a * pred_W[lane];
        #pragma unroll
        for (int o = 32; o > 0; o >>= 1) v += __shfl_xor(v, o);
        if (lane == 0) {
            float z = part1_s + v / gsum + pred_b[0];
            out[row] = 1.0f / (1.0f + __expf(-z));
        }
    }
}

extern "C" void kernel_launch(void* const* d_in, const int* in_sizes, int n_in,
                              void* d_out, int out_size, void* d_ws, size_t ws_size,
                              hipStream_t stream)
{
    const float* dense_x = (const float*)d_in[0];
    const int*   sparse  = (const int*)  d_in[1];
    const float* emb     = (const float*)d_in[2];
    const float* attn_W  = (const float*)d_in[3];
    const float* attn_b  = (const float*)d_in[4];
    const float* proj_W  = (const float*)d_in[5];
    const float* proj_b  = (const float*)d_in[6];
    const float* lin_W   = (const float*)d_in[7];
    const float* lin_b   = (const float*)d_in[8];
    const float* pred_W  = (const float*)d_in[9];
    const float* pred_b  = (const float*)d_in[10];
    float* out = (float*)d_out;

    int rows = in_sizes[0] / N_DENSE;   // 8192
    afm_kernel<<<rows, BLOCK, 0, stream>>>(dense_x, sparse, emb, attn_W, attn_b,
                                           proj_W, proj_b, lin_W, lin_b,
                                           pred_W, pred_b, out);
}